// Round 1
// baseline (11226.410 us; speedup 1.0000x reference)
//
#include <hip/hip_runtime.h>
#include <hip/hip_fp16.h>

// EncoderRNN: V=29, H=1024, L=4, B=64, S=512. Inputs/out are FLOAT32 (proven R1/R2).
#define Vn 29
#define Hn 1024
#define Ln 4
#define Bn 64
#define Sn 512
#define BH (Bn * Hn)
#define NBLK 256

typedef _Float16 half8 __attribute__((ext_vector_type(8)));
typedef _Float16 half4v __attribute__((ext_vector_type(4)));
typedef float f32x16 __attribute__((ext_vector_type(16)));
typedef float f32x4 __attribute__((ext_vector_type(4)));
typedef int i32x4 __attribute__((ext_vector_type(4)));

__device__ __forceinline__ float sigmf(float x) { return 1.0f / (1.0f + __expf(-x)); }
__device__ __forceinline__ float tanhf_(float x) { return 1.0f - 2.0f / (__expf(2.0f * x) + 1.0f); }

// --- LLC-coherent 16B load (bypass L1+L2, device coherence point), schedulable
// as a plain VMEM op; waitcnt discipline is OURS (see vwait*).
__device__ __forceinline__ half8 ldg_llc(const _Float16* p) {
    half8 v;
    asm volatile("global_load_dwordx4 %0, %1, off sc0 sc1" : "=v"(v) : "v"(p) : "memory");
    return v;
}
// 8B LLC-coherent load, asm-pinned issue point (used to hoist the y-carry load
// above the K-loop; asm volatile order is preserved vs the K-loop's asm loads).
__device__ __forceinline__ half4v ldg_llc4(const _Float16* p) {
    half4v v;
    asm volatile("global_load_dwordx2 %0, %1, off sc0 sc1" : "=v"(v) : "v"(p) : "memory");
    return v;
}
// Wait until <=CNT vector-mem ops outstanding; ties operands so dependent MFMAs
// cannot be scheduled above the wait. Extra earlier VMEM ops only make this
// conservative (vmcnt retires in issue order).
template <int CNT>
__device__ __forceinline__ void vwait1(half8& a) {
    asm volatile("s_waitcnt vmcnt(%1)" : "+v"(a) : "i"(CNT));
}
template <int CNT>
__device__ __forceinline__ void vwait2(half8& a, half8& b) {
    asm volatile("s_waitcnt vmcnt(%2)" : "+v"(a), "+v"(b) : "i"(CNT));
}

__device__ __forceinline__ void stg_coh4(_Float16* p, half4v v) {
    union { half4v h; unsigned long long u; } c;
    c.h = v;
    __hip_atomic_store((unsigned long long*)p, c.u, __ATOMIC_RELAXED,
                       __HIP_MEMORY_SCOPE_AGENT);
}

// flag region: 256 ints (one per block, monotonic step count), zeroed by init
#define BAR_INTS 320

__global__ void init_kernel(const float* __restrict__ bi, const float* __restrict__ bh,
                            const float* __restrict__ emb, int* __restrict__ bar,
                            float* __restrict__ biasf, _Float16* __restrict__ ehi,
                            _Float16* __restrict__ hbh) {
    int i = blockIdx.x * blockDim.x + threadIdx.x;
    int stride = gridDim.x * blockDim.x;
    for (int k = i; k < BAR_INTS; k += stride) bar[k] = 0;
    for (int k = i; k < Ln * 4 * Hn; k += stride) biasf[k] = bi[k] + bh[k];
    for (int k = i; k < Vn * Hn; k += stride)
        ehi[k] = (_Float16)((k < Hn) ? 0.f : emb[k]);  // padding_idx=0 row zero
    for (int k = i; k < 2 * Ln * Bn * Hn; k += stride) hbh[k] = (_Float16)0.f;
}

// Grid barrier, all-read flag protocol: each block publishes flag[bid]=target
// (monotonic, no reset, no atomics), wave 0 polls all 256 flags with one
// dwordx4/lane. 1-hop detection (last store -> observe) vs the old 2-hop
// atomic-tree + central release.
__device__ __forceinline__ void grid_barrier(int* __restrict__ bar, int bid, int target) {
    asm volatile("s_waitcnt vmcnt(0)" ::: "memory");  // drain this wave's stores
    __syncthreads();                                   // all waves drained
    if (threadIdx.x < 64) {
        if (threadIdx.x == 0)
            __hip_atomic_store(bar + bid, target, __ATOMIC_RELAXED, __HIP_MEMORY_SCOPE_AGENT);
        const int* p = bar + threadIdx.x * 4;
        long long t0 = clock64();
        int it = 0;
        for (;;) {
            i32x4 f;
            asm volatile("global_load_dwordx4 %0, %1, off sc0 sc1\n\t"
                         "s_waitcnt vmcnt(0)"
                         : "=v"(f) : "v"(p) : "memory");
            int m01 = f[0] < f[1] ? f[0] : f[1];
            int m23 = f[2] < f[3] ? f[2] : f[3];
            int m = m01 < m23 ? m01 : m23;
            if (__all(m >= target)) break;
            if (((++it) & 255) == 0 && clock64() - t0 > 2000000000LL) break;  // escape
        }
    }
    __syncthreads();
}

// ---- software-pipelined coherent K-loop: window of 8 chunk-pairs in flight.
template <int KS, int MT>
struct KStep {
    static __device__ __forceinline__ void run(const _Float16* a0, const _Float16* a1,
                                               half8 (&b0)[8], half8 (&b1)[8],
                                               const half8 (&wf)[2][16],
                                               f32x16 (&acc)[MT][2]) {
        constexpr int slot = KS & 7;
        constexpr int CNT = MT * ((KS + 8 < 16) ? 7 : (15 - KS));
        if constexpr (MT == 2) vwait2<CNT>(b0[slot], b1[slot]);
        else vwait1<CNT>(b0[slot]);
        acc[0][0] = __builtin_amdgcn_mfma_f32_32x32x16_f16(b0[slot], wf[0][KS], acc[0][0], 0, 0, 0);
        acc[0][1] = __builtin_amdgcn_mfma_f32_32x32x16_f16(b0[slot], wf[1][KS], acc[0][1], 0, 0, 0);
        if constexpr (MT == 2) {
            acc[1][0] = __builtin_amdgcn_mfma_f32_32x32x16_f16(b1[slot], wf[0][KS], acc[1][0], 0, 0, 0);
            acc[1][1] = __builtin_amdgcn_mfma_f32_32x32x16_f16(b1[slot], wf[1][KS], acc[1][1], 0, 0, 0);
        }
        if constexpr (KS + 8 < 16) {
            b0[slot] = ldg_llc(a0 + (KS + 8) * 16);
            if constexpr (MT == 2) b1[slot] = ldg_llc(a1 + (KS + 8) * 16);
        }
        KStep<KS + 1, MT>::run(a0, a1, b0, b1, wf, acc);
    }
};
template <int MT>
struct KStep<16, MT> {
    static __device__ __forceinline__ void run(const _Float16*, const _Float16*, half8 (&)[8],
                                               half8 (&)[8], const half8 (&)[2][16],
                                               f32x16 (&)[MT][2]) {}
};

template <int MT>
__device__ __forceinline__ void cell_compute_coh(const _Float16* a0, const _Float16* a1,
                                                 const half8 (&wf)[2][16],
                                                 f32x16 (&acc)[MT][2]) {
#pragma unroll
    for (int mt = 0; mt < MT; ++mt)
#pragma unroll
        for (int nt = 0; nt < 2; ++nt)
#pragma unroll
            for (int r = 0; r < 16; ++r) acc[mt][nt][r] = 0.f;
    half8 b0[8], b1[8];
#pragma unroll
    for (int i = 0; i < 8; ++i) {
        b0[i] = ldg_llc(a0 + i * 16);
        if constexpr (MT == 2) b1[i] = ldg_llc(a1 + i * 16);
    }
    KStep<0, MT>::run(a0, a1, b0, b1, wf, acc);
}

// plain-cached path (layer-0 embedding reads): compiler-scheduled loads
template <int MT>
__device__ __forceinline__ void cell_compute_plain(const _Float16* __restrict__ a0,
                                                   const _Float16* __restrict__ a1,
                                                   const half8 (&wf)[2][16],
                                                   f32x16 (&acc)[MT][2]) {
#pragma unroll
    for (int mt = 0; mt < MT; ++mt)
#pragma unroll
        for (int nt = 0; nt < 2; ++nt)
#pragma unroll
            for (int r = 0; r < 16; ++r) acc[mt][nt][r] = 0.f;
#pragma unroll
    for (int ks = 0; ks < 16; ++ks) {
        half8 x0 = *reinterpret_cast<const half8*>(a0 + ks * 16);
        acc[0][0] = __builtin_amdgcn_mfma_f32_32x32x16_f16(x0, wf[0][ks], acc[0][0], 0, 0, 0);
        acc[0][1] = __builtin_amdgcn_mfma_f32_32x32x16_f16(x0, wf[1][ks], acc[0][1], 0, 0, 0);
        if (MT == 2) {
            half8 x1 = *reinterpret_cast<const half8*>(a1 + ks * 16);
            acc[1][0] = __builtin_amdgcn_mfma_f32_32x32x16_f16(x1, wf[0][ks], acc[1][0], 0, 0, 0);
            acc[1][1] = __builtin_amdgcn_mfma_f32_32x32x16_f16(x1, wf[1][ks], acc[1][1], 0, 0, 0);
        }
    }
}

// part write: C layout (32x32): n=lane&31, m=4*(lane>>5)+(r&3)+8*(r>>2)
template <int MT, bool ADD>
__device__ __forceinline__ void part_write(float (*pw)[64], const f32x16 (&acc)[MT][2],
                                           int lane) {
    const int ln = lane & 31;
#pragma unroll
    for (int mt = 0; mt < MT; ++mt)
#pragma unroll
        for (int nt = 0; nt < 2; ++nt)
#pragma unroll
            for (int r = 0; r < 16; ++r) {
                int m = mt * 32 + 4 * (lane >> 5) + (r & 3) + 8 * (r >> 2);
                int n = nt * 32 + ln;
                int idx = n ^ ((m & 7) << 2);
                if (ADD) pw[m][idx] += acc[mt][nt][r];
                else pw[m][idx] = acc[mt][nt][r];
            }
}

// Persistent wavefront LSTM: 256 blocks x 512 threads (8 waves, 2/SIMD).
// Wave w: K-slice 256 (w<4: y/w_ih, w>=4: h/w_hh), full N=64.
__global__ __launch_bounds__(512, 2) void lstm_persistent(
    const int* __restrict__ padded_in, const int* __restrict__ in_lengths,
    const float* __restrict__ w_ih, const float* __restrict__ w_hh,
    const float* __restrict__ biasf, int* __restrict__ bar,
    const _Float16* __restrict__ ehi, _Float16* __restrict__ hbh,
    _Float16* __restrict__ ybh, float* __restrict__ out) {
    __shared__ __align__(16) float part[4][64][64];  // 64 KB

    const int cu = blockIdx.x;
    const int layer = cu >> 6;
    const int j0 = (cu & 63) * 16;
    const int tid = threadIdx.x;
    const int wv = tid >> 6;
    const int lane = tid & 63;
    const int ln = lane & 31;
    const int khalf = (lane >> 5) * 8;
    const bool isH = (wv >= 4);
    const int kb = (isH ? (wv - 4) : wv) * 256;

    // ---- one-time weight preload: fp32 -> fp16 frags, 128 VGPR/lane
    half8 wf[2][16];
    {
        const float* wsrc = isH ? w_hh : w_ih;
#pragma unroll
        for (int nt = 0; nt < 2; ++nt) {
            int n = nt * 32 + ln;
            const float* rowp =
                wsrc + ((size_t)layer * 4 * Hn + (n >> 4) * Hn + j0 + (n & 15)) * Hn + kb + khalf;
#pragma unroll
            for (int ks = 0; ks < 16; ++ks) {
                f32x4 a = *reinterpret_cast<const f32x4*>(rowp + ks * 16);
                f32x4 b = *reinterpret_cast<const f32x4*>(rowp + ks * 16 + 4);
                half8 h;
                h[0] = (_Float16)a[0]; h[1] = (_Float16)a[1];
                h[2] = (_Float16)a[2]; h[3] = (_Float16)a[3];
                h[4] = (_Float16)b[0]; h[5] = (_Float16)b[1];
                h[6] = (_Float16)b[2]; h[7] = (_Float16)b[3];
                wf[nt][ks] = h;
            }
        }
    }

    // epilogue ownership (threads 0..255): batch row brow, 4 units jcol..jcol+3
    const int brow = (tid & 255) >> 2;
    const int jcol = (tid & 3) * 4;
    const int J = j0 + jcol;
    float bias[4][4];
#pragma unroll
    for (int g = 0; g < 4; ++g)
#pragma unroll
        for (int p = 0; p < 4; ++p)
            bias[g][p] = biasf[layer * 4096 + g * 1024 + J + p];

    float creg[4] = {0.f, 0.f, 0.f, 0.f};
    float hreg[4] = {0.f, 0.f, 0.f, 0.f};

    const bool carryOwner = (tid < 256) && (layer > 0) && (layer < 3);

    for (int w = 0; w < Sn + Ln - 1; ++w) {
        const int t = w - layer;
        if (t >= 0 && t < Sn) {
            const int bs = in_lengths[t];
            const int pin = t & 1;
            const int pout = pin ^ 1;

            // early-issue inactive-row y-carry load (layers 1-2): pinned above
            // the K-loop asm loads so its LLC latency hides under compute.
            half4v ycarry{};
            if (carryOwner)
                ycarry = ldg_llc4(&ybh[((size_t)(pin * 3 + layer - 1) * Bn + brow) * Hn + J]);

            // per-wave A-source pointers for its K-slice
            const _Float16 *a0, *a1;
            bool coh;
            if (!isH) {
                const int ko = kb + khalf;
                if (layer == 0) {  // embedding: read-only, cacheable
                    a0 = ehi + (size_t)padded_in[ln * Sn + t] * Hn + ko;
                    a1 = ehi + (size_t)padded_in[(32 + ln) * Sn + t] * Hn + ko;
                    coh = false;
                } else {
                    size_t base = (size_t)(pin * 3 + layer - 1) * BH + ko;
                    a0 = ybh + base + (size_t)ln * Hn;
                    a1 = ybh + base + (size_t)(32 + ln) * Hn;
                    coh = true;
                }
            } else {
                size_t base = (size_t)(pin * Ln + layer) * BH + kb + khalf;
                a0 = hbh + base + (size_t)ln * Hn;
                a1 = hbh + base + (size_t)(32 + ln) * Hn;
                coh = true;
            }

            // compute; two-phase partial accumulation (waves 0-3 store, 4-7 add)
            if (bs > 32) {
                f32x16 acc[2][2];
                if (coh) cell_compute_coh<2>(a0, a1, wf, acc);
                else cell_compute_plain<2>(a0, a1, wf, acc);
                if (wv < 4) part_write<2, false>(part[wv], acc, lane);
                __syncthreads();
                if (wv >= 4) part_write<2, true>(part[wv - 4], acc, lane);
            } else {
                f32x16 acc[1][2];
                if (coh) cell_compute_coh<1>(a0, a1, wf, acc);
                else cell_compute_plain<1>(a0, a1, wf, acc);
                if (wv < 4) part_write<1, false>(part[wv], acc, lane);
                __syncthreads();
                if (wv >= 4) part_write<1, true>(part[wv - 4], acc, lane);
            }
            __syncthreads();

            if (tid < 256) {
                // cross-wave K-reduction + bias
                float gsum[4][4];
#pragma unroll
                for (int g = 0; g < 4; ++g) {
                    int nidx = (g * 16 + jcol) ^ ((brow & 7) << 2);
                    f32x4 s = *reinterpret_cast<const f32x4*>(&part[0][brow][nidx]);
#pragma unroll
                    for (int p2 = 1; p2 < 4; ++p2)
                        s = s + *reinterpret_cast<const f32x4*>(&part[p2][brow][nidx]);
#pragma unroll
                    for (int p = 0; p < 4; ++p) gsum[g][p] = s[p] + bias[g][p];
                }

                const bool active = (brow < bs);
                float hold[4], ysum[4];
#pragma unroll
                for (int p = 0; p < 4; ++p) {
                    float cn = sigmf(gsum[1][p]) * creg[p] + sigmf(gsum[0][p]) * tanhf_(gsum[2][p]);
                    float hn = sigmf(gsum[3][p]) * tanhf_(cn);
                    hold[p] = hreg[p];
                    if (active) { creg[p] = cn; hreg[p] = hn; }
                    ysum[p] = hreg[p] + hold[p];
                }
                {   // h broadcast (fp16, t-parity double buffer) -> LLC
                    half4v hh;
#pragma unroll
                    for (int p = 0; p < 4; ++p) hh[p] = (_Float16)hreg[p];
                    stg_coh4(&hbh[((size_t)(pout * Ln + layer) * Bn + brow) * Hn + J], hh);
                }
                if (layer < 3) {  // y interface feed (same-parity slot) -> LLC
                    half4v yh;
                    if (active) {
#pragma unroll
                        for (int p = 0; p < 4; ++p) yh[p] = (_Float16)ysum[p];
                    } else {  // carry incoming y (x_t for l=0) verbatim
                        if (layer == 0) {
                            int ib = padded_in[brow * Sn + t];
                            yh = *reinterpret_cast<const half4v*>(&ehi[(size_t)ib * Hn + J]);
                        } else {
                            yh = ycarry;  // pre-issued at step start
                        }
                    }
                    stg_coh4(&ybh[((size_t)(pin * 3 + layer) * Bn + brow) * Hn + J], yh);
                }
            }
        }
        grid_barrier(bar, cu, w + 1);
    }

    if (layer == 3 && tid < 256) {
        f32x4 o;
#pragma unroll
        for (int p = 0; p < 4; ++p) o[p] = hreg[p];
        *reinterpret_cast<f32x4*>(&out[(size_t)brow * Hn + J]) = o;
    }
}

extern "C" void kernel_launch(void* const* d_in, const int* in_sizes, int n_in,
                              void* d_out, int out_size, void* d_ws, size_t ws_size,
                              hipStream_t stream) {
    const int* padded_in = (const int*)d_in[0];
    const int* in_lengths = (const int*)d_in[1];
    const float* emb = (const float*)d_in[2];
    const float* w_ih = (const float*)d_in[3];
    const float* w_hh = (const float*)d_in[4];
    const float* b_ih = (const float*)d_in[5];
    const float* b_hh = (const float*)d_in[6];
    float* outp = (float*)d_out;

    // workspace (~2 MB), all segments 16B-aligned
    char* w = (char*)d_ws;
    int* bar = (int*)w;            w += BAR_INTS * 4;
    float* biasf = (float*)w;      w += (size_t)Ln * 4 * Hn * 4;
    _Float16* ehi = (_Float16*)w;  w += (size_t)Vn * Hn * 2;
    _Float16* hbh = (_Float16*)w;  w += (size_t)2 * Ln * Bn * Hn * 2;
    _Float16* ybh = (_Float16*)w;  w += (size_t)2 * 3 * Bn * Hn * 2;

    init_kernel<<<256, 256, 0, stream>>>(b_ih, b_hh, emb, bar, biasf, ehi, hbh);
    lstm_persistent<<<NBLK, 512, 0, stream>>>(padded_in, in_lengths, w_ih, w_hh, biasf, bar,
                                              ehi, hbh, ybh, outp);
}

// Round 2
// 8814.163 us; speedup vs baseline: 1.2737x; 1.2737x over previous
//
#include <hip/hip_runtime.h>
#include <hip/hip_fp16.h>

// EncoderRNN: V=29, H=1024, L=4, B=64, S=512. Inputs/out are FLOAT32 (proven R1/R2).
#define Vn 29
#define Hn 1024
#define Ln 4
#define Bn 64
#define Sn 512
#define BH (Bn * Hn)
#define NBLK 256

typedef _Float16 half8 __attribute__((ext_vector_type(8)));
typedef _Float16 half4v __attribute__((ext_vector_type(4)));
typedef float f32x16 __attribute__((ext_vector_type(16)));
typedef float f32x4 __attribute__((ext_vector_type(4)));

__device__ __forceinline__ float sigmf(float x) { return 1.0f / (1.0f + __expf(-x)); }
__device__ __forceinline__ float tanhf_(float x) { return 1.0f - 2.0f / (__expf(2.0f * x) + 1.0f); }

// --- LLC-coherent 16B load (bypass L1+L2, device coherence point), schedulable
// as a plain VMEM op; waitcnt discipline is OURS (see vwait*).
__device__ __forceinline__ half8 ldg_llc(const _Float16* p) {
    half8 v;
    asm volatile("global_load_dwordx4 %0, %1, off sc0 sc1" : "=v"(v) : "v"(p) : "memory");
    return v;
}
// 8B LLC-coherent load, asm-pinned issue point (used to hoist the y-carry load
// above the K-loop; asm volatile order is preserved vs the K-loop's asm loads).
__device__ __forceinline__ half4v ldg_llc4(const _Float16* p) {
    half4v v;
    asm volatile("global_load_dwordx2 %0, %1, off sc0 sc1" : "=v"(v) : "v"(p) : "memory");
    return v;
}
// Wait until <=CNT vector-mem ops outstanding; ties operands so dependent MFMAs
// cannot be scheduled above the wait. Extra earlier VMEM ops only make this
// conservative (vmcnt retires in issue order).
template <int CNT>
__device__ __forceinline__ void vwait1(half8& a) {
    asm volatile("s_waitcnt vmcnt(%1)" : "+v"(a) : "i"(CNT));
}
template <int CNT>
__device__ __forceinline__ void vwait2(half8& a, half8& b) {
    asm volatile("s_waitcnt vmcnt(%2)" : "+v"(a), "+v"(b) : "i"(CNT));
}

__device__ __forceinline__ void stg_coh4(_Float16* p, half4v v) {
    union { half4v h; unsigned long long u; } c;
    c.h = v;
    __hip_atomic_store((unsigned long long*)p, c.u, __ATOMIC_RELAXED,
                       __HIP_MEMORY_SCOPE_AGENT);
}

// barrier block: c0[8] padded 32 ints apart (0..255), c1 at [256], gen at [288]
#define BAR_INTS 320

__global__ void init_kernel(const float* __restrict__ bi, const float* __restrict__ bh,
                            const float* __restrict__ emb, int* __restrict__ bar,
                            float* __restrict__ biasf, _Float16* __restrict__ ehi,
                            _Float16* __restrict__ hbh) {
    int i = blockIdx.x * blockDim.x + threadIdx.x;
    int stride = gridDim.x * blockDim.x;
    for (int k = i; k < BAR_INTS; k += stride) bar[k] = 0;
    for (int k = i; k < Ln * 4 * Hn; k += stride) biasf[k] = bi[k] + bh[k];
    for (int k = i; k < Vn * Hn; k += stride)
        ehi[k] = (_Float16)((k < Hn) ? 0.f : emb[k]);  // padding_idx=0 row zero
    for (int k = i; k < 2 * Ln * Bn * Hn; k += stride) hbh[k] = (_Float16)0.f;
}

// Grid barrier, zero cache-maintenance: relaxed agent atomics only (proven).
// Atomic-tree arrival (8 groups of 32) + central gen release; single poller
// thread per block with s_sleep backoff. R1 lesson: all-lane flag polling
// floods the LLC path (+4.3 GB/dispatch) -- do NOT widen the poll set.
__device__ __forceinline__ void grid_barrier(int* __restrict__ bar, int bid) {
    asm volatile("s_waitcnt vmcnt(0)" ::: "memory");  // drain this wave's stores
    __syncthreads();
    if (threadIdx.x == 0) {
        int* c0 = bar + (bid & 7) * 32;
        int* c1 = bar + 256;
        int* gen = bar + 288;
        int my = __hip_atomic_load(gen, __ATOMIC_RELAXED, __HIP_MEMORY_SCOPE_AGENT);
        bool rel = false;
        int p = __hip_atomic_fetch_add(c0, 1, __ATOMIC_RELAXED, __HIP_MEMORY_SCOPE_AGENT);
        if (p == 31) {
            int q = __hip_atomic_fetch_add(c1, 1, __ATOMIC_RELAXED, __HIP_MEMORY_SCOPE_AGENT);
            if (q == 7) {  // reset-before-release; vmcnt drain orders resets < gen
                for (int g = 0; g < 8; ++g)
                    __hip_atomic_store(bar + g * 32, 0, __ATOMIC_RELAXED,
                                       __HIP_MEMORY_SCOPE_AGENT);
                __hip_atomic_store(c1, 0, __ATOMIC_RELAXED, __HIP_MEMORY_SCOPE_AGENT);
                asm volatile("s_waitcnt vmcnt(0)" ::: "memory");
                __hip_atomic_store(gen, my + 1, __ATOMIC_RELAXED, __HIP_MEMORY_SCOPE_AGENT);
                rel = true;
            }
        }
        if (!rel) {
            long long t0 = clock64();
            int it = 0;
            while (__hip_atomic_load(gen, __ATOMIC_RELAXED, __HIP_MEMORY_SCOPE_AGENT) == my) {
                __builtin_amdgcn_s_sleep(1);
                if (((++it) & 255) == 0 && clock64() - t0 > 2000000000LL) break;  // escape
            }
        }
    }
    __syncthreads();
}

// ---- software-pipelined coherent K-loop: window of 8 chunk-pairs in flight.
template <int KS, int MT>
struct KStep {
    static __device__ __forceinline__ void run(const _Float16* a0, const _Float16* a1,
                                               half8 (&b0)[8], half8 (&b1)[8],
                                               const half8 (&wf)[2][16],
                                               f32x16 (&acc)[MT][2]) {
        constexpr int slot = KS & 7;
        constexpr int CNT = MT * ((KS + 8 < 16) ? 7 : (15 - KS));
        if constexpr (MT == 2) vwait2<CNT>(b0[slot], b1[slot]);
        else vwait1<CNT>(b0[slot]);
        acc[0][0] = __builtin_amdgcn_mfma_f32_32x32x16_f16(b0[slot], wf[0][KS], acc[0][0], 0, 0, 0);
        acc[0][1] = __builtin_amdgcn_mfma_f32_32x32x16_f16(b0[slot], wf[1][KS], acc[0][1], 0, 0, 0);
        if constexpr (MT == 2) {
            acc[1][0] = __builtin_amdgcn_mfma_f32_32x32x16_f16(b1[slot], wf[0][KS], acc[1][0], 0, 0, 0);
            acc[1][1] = __builtin_amdgcn_mfma_f32_32x32x16_f16(b1[slot], wf[1][KS], acc[1][1], 0, 0, 0);
        }
        if constexpr (KS + 8 < 16) {
            b0[slot] = ldg_llc(a0 + (KS + 8) * 16);
            if constexpr (MT == 2) b1[slot] = ldg_llc(a1 + (KS + 8) * 16);
        }
        KStep<KS + 1, MT>::run(a0, a1, b0, b1, wf, acc);
    }
};
template <int MT>
struct KStep<16, MT> {
    static __device__ __forceinline__ void run(const _Float16*, const _Float16*, half8 (&)[8],
                                               half8 (&)[8], const half8 (&)[2][16],
                                               f32x16 (&)[MT][2]) {}
};

template <int MT>
__device__ __forceinline__ void cell_compute_coh(const _Float16* a0, const _Float16* a1,
                                                 const half8 (&wf)[2][16],
                                                 f32x16 (&acc)[MT][2]) {
#pragma unroll
    for (int mt = 0; mt < MT; ++mt)
#pragma unroll
        for (int nt = 0; nt < 2; ++nt)
#pragma unroll
            for (int r = 0; r < 16; ++r) acc[mt][nt][r] = 0.f;
    half8 b0[8], b1[8];
#pragma unroll
    for (int i = 0; i < 8; ++i) {
        b0[i] = ldg_llc(a0 + i * 16);
        if constexpr (MT == 2) b1[i] = ldg_llc(a1 + i * 16);
    }
    KStep<0, MT>::run(a0, a1, b0, b1, wf, acc);
}

// plain-cached path (layer-0 embedding reads): compiler-scheduled loads
template <int MT>
__device__ __forceinline__ void cell_compute_plain(const _Float16* __restrict__ a0,
                                                   const _Float16* __restrict__ a1,
                                                   const half8 (&wf)[2][16],
                                                   f32x16 (&acc)[MT][2]) {
#pragma unroll
    for (int mt = 0; mt < MT; ++mt)
#pragma unroll
        for (int nt = 0; nt < 2; ++nt)
#pragma unroll
            for (int r = 0; r < 16; ++r) acc[mt][nt][r] = 0.f;
#pragma unroll
    for (int ks = 0; ks < 16; ++ks) {
        half8 x0 = *reinterpret_cast<const half8*>(a0 + ks * 16);
        acc[0][0] = __builtin_amdgcn_mfma_f32_32x32x16_f16(x0, wf[0][ks], acc[0][0], 0, 0, 0);
        acc[0][1] = __builtin_amdgcn_mfma_f32_32x32x16_f16(x0, wf[1][ks], acc[0][1], 0, 0, 0);
        if (MT == 2) {
            half8 x1 = *reinterpret_cast<const half8*>(a1 + ks * 16);
            acc[1][0] = __builtin_amdgcn_mfma_f32_32x32x16_f16(x1, wf[0][ks], acc[1][0], 0, 0, 0);
            acc[1][1] = __builtin_amdgcn_mfma_f32_32x32x16_f16(x1, wf[1][ks], acc[1][1], 0, 0, 0);
        }
    }
}

// part write: C layout (32x32): n=lane&31, m=4*(lane>>5)+(r&3)+8*(r>>2)
template <int MT, bool ADD>
__device__ __forceinline__ void part_write(float (*pw)[64], const f32x16 (&acc)[MT][2],
                                           int lane) {
    const int ln = lane & 31;
#pragma unroll
    for (int mt = 0; mt < MT; ++mt)
#pragma unroll
        for (int nt = 0; nt < 2; ++nt)
#pragma unroll
            for (int r = 0; r < 16; ++r) {
                int m = mt * 32 + 4 * (lane >> 5) + (r & 3) + 8 * (r >> 2);
                int n = nt * 32 + ln;
                int idx = n ^ ((m & 7) << 2);
                if (ADD) pw[m][idx] += acc[mt][nt][r];
                else pw[m][idx] = acc[mt][nt][r];
            }
}

// Persistent wavefront LSTM: 256 blocks x 512 threads (8 waves, 2/SIMD).
// Wave w: K-slice 256 (w<4: y/w_ih, w>=4: h/w_hh), full N=64.
__global__ __launch_bounds__(512, 2) void lstm_persistent(
    const int* __restrict__ padded_in, const int* __restrict__ in_lengths,
    const float* __restrict__ w_ih, const float* __restrict__ w_hh,
    const float* __restrict__ biasf, int* __restrict__ bar,
    const _Float16* __restrict__ ehi, _Float16* __restrict__ hbh,
    _Float16* __restrict__ ybh, float* __restrict__ out) {
    __shared__ __align__(16) float part[4][64][64];  // 64 KB

    const int cu = blockIdx.x;
    const int layer = cu >> 6;
    const int j0 = (cu & 63) * 16;
    const int tid = threadIdx.x;
    const int wv = tid >> 6;
    const int lane = tid & 63;
    const int ln = lane & 31;
    const int khalf = (lane >> 5) * 8;
    const bool isH = (wv >= 4);
    const int kb = (isH ? (wv - 4) : wv) * 256;

    // ---- one-time weight preload: fp32 -> fp16 frags, 128 VGPR/lane
    half8 wf[2][16];
    {
        const float* wsrc = isH ? w_hh : w_ih;
#pragma unroll
        for (int nt = 0; nt < 2; ++nt) {
            int n = nt * 32 + ln;
            const float* rowp =
                wsrc + ((size_t)layer * 4 * Hn + (n >> 4) * Hn + j0 + (n & 15)) * Hn + kb + khalf;
#pragma unroll
            for (int ks = 0; ks < 16; ++ks) {
                f32x4 a = *reinterpret_cast<const f32x4*>(rowp + ks * 16);
                f32x4 b = *reinterpret_cast<const f32x4*>(rowp + ks * 16 + 4);
                half8 h;
                h[0] = (_Float16)a[0]; h[1] = (_Float16)a[1];
                h[2] = (_Float16)a[2]; h[3] = (_Float16)a[3];
                h[4] = (_Float16)b[0]; h[5] = (_Float16)b[1];
                h[6] = (_Float16)b[2]; h[7] = (_Float16)b[3];
                wf[nt][ks] = h;
            }
        }
    }

    // epilogue ownership (threads 0..255): batch row brow, 4 units jcol..jcol+3
    const int brow = (tid & 255) >> 2;
    const int jcol = (tid & 3) * 4;
    const int J = j0 + jcol;
    float bias[4][4];
#pragma unroll
    for (int g = 0; g < 4; ++g)
#pragma unroll
        for (int p = 0; p < 4; ++p)
            bias[g][p] = biasf[layer * 4096 + g * 1024 + J + p];

    float creg[4] = {0.f, 0.f, 0.f, 0.f};
    float hreg[4] = {0.f, 0.f, 0.f, 0.f};

    const bool carryOwner = (tid < 256) && (layer > 0) && (layer < 3);

    for (int w = 0; w < Sn + Ln - 1; ++w) {
        const int t = w - layer;
        if (t >= 0 && t < Sn) {
            const int bs = in_lengths[t];
            const int pin = t & 1;
            const int pout = pin ^ 1;

            // early-issue inactive-row y-carry load (layers 1-2): pinned above
            // the K-loop asm loads so its LLC latency hides under compute.
            half4v ycarry{};
            if (carryOwner)
                ycarry = ldg_llc4(&ybh[((size_t)(pin * 3 + layer - 1) * Bn + brow) * Hn + J]);

            // per-wave A-source pointers for its K-slice
            const _Float16 *a0, *a1;
            bool coh;
            if (!isH) {
                const int ko = kb + khalf;
                if (layer == 0) {  // embedding: read-only, cacheable
                    a0 = ehi + (size_t)padded_in[ln * Sn + t] * Hn + ko;
                    a1 = ehi + (size_t)padded_in[(32 + ln) * Sn + t] * Hn + ko;
                    coh = false;
                } else {
                    size_t base = (size_t)(pin * 3 + layer - 1) * BH + ko;
                    a0 = ybh + base + (size_t)ln * Hn;
                    a1 = ybh + base + (size_t)(32 + ln) * Hn;
                    coh = true;
                }
            } else {
                size_t base = (size_t)(pin * Ln + layer) * BH + kb + khalf;
                a0 = hbh + base + (size_t)ln * Hn;
                a1 = hbh + base + (size_t)(32 + ln) * Hn;
                coh = true;
            }

            // compute; two-phase partial accumulation (waves 0-3 store, 4-7 add)
            if (bs > 32) {
                f32x16 acc[2][2];
                if (coh) cell_compute_coh<2>(a0, a1, wf, acc);
                else cell_compute_plain<2>(a0, a1, wf, acc);
                if (wv < 4) part_write<2, false>(part[wv], acc, lane);
                __syncthreads();
                if (wv >= 4) part_write<2, true>(part[wv - 4], acc, lane);
            } else {
                f32x16 acc[1][2];
                if (coh) cell_compute_coh<1>(a0, a1, wf, acc);
                else cell_compute_plain<1>(a0, a1, wf, acc);
                if (wv < 4) part_write<1, false>(part[wv], acc, lane);
                __syncthreads();
                if (wv >= 4) part_write<1, true>(part[wv - 4], acc, lane);
            }
            __syncthreads();

            if (tid < 256) {
                // cross-wave K-reduction + bias
                float gsum[4][4];
#pragma unroll
                for (int g = 0; g < 4; ++g) {
                    int nidx = (g * 16 + jcol) ^ ((brow & 7) << 2);
                    f32x4 s = *reinterpret_cast<const f32x4*>(&part[0][brow][nidx]);
#pragma unroll
                    for (int p2 = 1; p2 < 4; ++p2)
                        s = s + *reinterpret_cast<const f32x4*>(&part[p2][brow][nidx]);
#pragma unroll
                    for (int p = 0; p < 4; ++p) gsum[g][p] = s[p] + bias[g][p];
                }

                const bool active = (brow < bs);
                float hold[4], ysum[4];
#pragma unroll
                for (int p = 0; p < 4; ++p) {
                    float cn = sigmf(gsum[1][p]) * creg[p] + sigmf(gsum[0][p]) * tanhf_(gsum[2][p]);
                    float hn = sigmf(gsum[3][p]) * tanhf_(cn);
                    hold[p] = hreg[p];
                    if (active) { creg[p] = cn; hreg[p] = hn; }
                    ysum[p] = hreg[p] + hold[p];
                }
                {   // h broadcast (fp16, t-parity double buffer) -> LLC
                    half4v hh;
#pragma unroll
                    for (int p = 0; p < 4; ++p) hh[p] = (_Float16)hreg[p];
                    stg_coh4(&hbh[((size_t)(pout * Ln + layer) * Bn + brow) * Hn + J], hh);
                }
                if (layer < 3) {  // y interface feed (same-parity slot) -> LLC
                    half4v yh;
                    if (active) {
#pragma unroll
                        for (int p = 0; p < 4; ++p) yh[p] = (_Float16)ysum[p];
                    } else {  // carry incoming y (x_t for l=0) verbatim
                        if (layer == 0) {
                            int ib = padded_in[brow * Sn + t];
                            yh = *reinterpret_cast<const half4v*>(&ehi[(size_t)ib * Hn + J]);
                        } else {
                            yh = ycarry;  // pre-issued at step start
                        }
                    }
                    stg_coh4(&ybh[((size_t)(pin * 3 + layer) * Bn + brow) * Hn + J], yh);
                }
            }
        }
        grid_barrier(bar, cu);
    }

    if (layer == 3 && tid < 256) {
        f32x4 o;
#pragma unroll
        for (int p = 0; p < 4; ++p) o[p] = hreg[p];
        *reinterpret_cast<f32x4*>(&out[(size_t)brow * Hn + J]) = o;
    }
}

extern "C" void kernel_launch(void* const* d_in, const int* in_sizes, int n_in,
                              void* d_out, int out_size, void* d_ws, size_t ws_size,
                              hipStream_t stream) {
    const int* padded_in = (const int*)d_in[0];
    const int* in_lengths = (const int*)d_in[1];
    const float* emb = (const float*)d_in[2];
    const float* w_ih = (const float*)d_in[3];
    const float* w_hh = (const float*)d_in[4];
    const float* b_ih = (const float*)d_in[5];
    const float* b_hh = (const float*)d_in[6];
    float* outp = (float*)d_out;

    // workspace (~2 MB), all segments 16B-aligned
    char* w = (char*)d_ws;
    int* bar = (int*)w;            w += BAR_INTS * 4;
    float* biasf = (float*)w;      w += (size_t)Ln * 4 * Hn * 4;
    _Float16* ehi = (_Float16*)w;  w += (size_t)Vn * Hn * 2;
    _Float16* hbh = (_Float16*)w;  w += (size_t)2 * Ln * Bn * Hn * 2;
    _Float16* ybh = (_Float16*)w;  w += (size_t)2 * 3 * Bn * Hn * 2;

    init_kernel<<<256, 256, 0, stream>>>(b_ih, b_hh, emb, bar, biasf, ehi, hbh);
    lstm_persistent<<<NBLK, 512, 0, stream>>>(padded_in, in_lengths, w_ih, w_hh, biasf, bar,
                                              ehi, hbh, ybh, outp);
}

// Round 3
// 7779.428 us; speedup vs baseline: 1.4431x; 1.1330x over previous
//
#include <hip/hip_runtime.h>
#include <hip/hip_fp16.h>

// EncoderRNN: V=29, H=1024, L=4, B=64, S=512. Inputs/out are FLOAT32 (proven R1/R2).
#define Vn 29
#define Hn 1024
#define Ln 4
#define Bn 64
#define Sn 512
#define BH (Bn * Hn)
#define NBLK 256

typedef _Float16 half8 __attribute__((ext_vector_type(8)));
typedef _Float16 half4v __attribute__((ext_vector_type(4)));
typedef float f32x16 __attribute__((ext_vector_type(16)));
typedef float f32x4 __attribute__((ext_vector_type(4)));

__device__ __forceinline__ float sigmf(float x) { return 1.0f / (1.0f + __expf(-x)); }
__device__ __forceinline__ float tanhf_(float x) { return 1.0f - 2.0f / (__expf(2.0f * x) + 1.0f); }

// Wave-linear permuted layout for h/y interface buffers (we own both sides):
// element (row r, unit j) lives at half-offset
//   ((j>>4)*2 + (r>>5))*512 + (((j>>3)&1)*32 + (r&31))*8 + (j&7)
// so a K-loop wave-load of one MFMA A-fragment chunk is CONTIGUOUS 1 KB
// (lane l reads base + l*16B), 100% 64B-line utilization, and producers
// write full lines. Bit-permutation of (r[5:0], j[9:0]) -> bijective in BH.
__device__ __forceinline__ int perm_off(int r, int j) {
    return (((j >> 4) * 2 + (r >> 5)) << 9) + ((((j >> 3) & 1) << 5) + (r & 31)) * 8 + (j & 7);
}

// --- LLC-coherent 16B load (bypass L1+L2, device coherence point), schedulable
// as a plain VMEM op; waitcnt discipline is OURS (see vwait*).
__device__ __forceinline__ half8 ldg_llc(const _Float16* p) {
    half8 v;
    asm volatile("global_load_dwordx4 %0, %1, off sc0 sc1" : "=v"(v) : "v"(p) : "memory");
    return v;
}
// 8B LLC-coherent load, asm-pinned issue point (hoisted y-carry load).
__device__ __forceinline__ half4v ldg_llc4(const _Float16* p) {
    half4v v;
    asm volatile("global_load_dwordx2 %0, %1, off sc0 sc1" : "=v"(v) : "v"(p) : "memory");
    return v;
}
// Wait until <=CNT vector-mem ops outstanding; ties operands so dependent MFMAs
// cannot be scheduled above the wait. Extra EARLIER VMEM ops are harmless:
// vmcnt retires in issue order, so outstanding<=CNT implies our slot retired.
template <int CNT>
__device__ __forceinline__ void vwait1(half8& a) {
    asm volatile("s_waitcnt vmcnt(%1)" : "+v"(a) : "i"(CNT));
}
template <int CNT>
__device__ __forceinline__ void vwait2(half8& a, half8& b) {
    asm volatile("s_waitcnt vmcnt(%2)" : "+v"(a), "+v"(b) : "i"(CNT));
}

__device__ __forceinline__ void stg_coh4(_Float16* p, half4v v) {
    union { half4v h; unsigned long long u; } c;
    c.h = v;
    __hip_atomic_store((unsigned long long*)p, c.u, __ATOMIC_RELAXED,
                       __HIP_MEMORY_SCOPE_AGENT);
}

// barrier block: c0[8] padded 32 ints apart (0..255), c1 at [256], gen at [288]
#define BAR_INTS 320

__global__ void init_kernel(const float* __restrict__ bi, const float* __restrict__ bh,
                            const float* __restrict__ emb, int* __restrict__ bar,
                            float* __restrict__ biasf, _Float16* __restrict__ ehi,
                            _Float16* __restrict__ hbh) {
    int i = blockIdx.x * blockDim.x + threadIdx.x;
    int stride = gridDim.x * blockDim.x;
    for (int k = i; k < BAR_INTS; k += stride) bar[k] = 0;
    for (int k = i; k < Ln * 4 * Hn; k += stride) biasf[k] = bi[k] + bh[k];
    for (int k = i; k < Vn * Hn; k += stride)
        ehi[k] = (_Float16)((k < Hn) ? 0.f : emb[k]);  // padding_idx=0 row zero
    for (int k = i; k < 2 * Ln * Bn * Hn; k += stride) hbh[k] = (_Float16)0.f;
}

// Grid barrier, zero cache-maintenance: relaxed agent atomics only (proven).
// R1 lesson: all-lane flag polling floods the LLC path -- keep 1 poller/block.
__device__ __forceinline__ void grid_barrier(int* __restrict__ bar, int bid) {
    asm volatile("s_waitcnt vmcnt(0)" ::: "memory");  // drain this wave's stores
    __syncthreads();
    if (threadIdx.x == 0) {
        int* c0 = bar + (bid & 7) * 32;
        int* c1 = bar + 256;
        int* gen = bar + 288;
        int my = __hip_atomic_load(gen, __ATOMIC_RELAXED, __HIP_MEMORY_SCOPE_AGENT);
        bool rel = false;
        int p = __hip_atomic_fetch_add(c0, 1, __ATOMIC_RELAXED, __HIP_MEMORY_SCOPE_AGENT);
        if (p == 31) {
            int q = __hip_atomic_fetch_add(c1, 1, __ATOMIC_RELAXED, __HIP_MEMORY_SCOPE_AGENT);
            if (q == 7) {  // reset-before-release; vmcnt drain orders resets < gen
                for (int g = 0; g < 8; ++g)
                    __hip_atomic_store(bar + g * 32, 0, __ATOMIC_RELAXED,
                                       __HIP_MEMORY_SCOPE_AGENT);
                __hip_atomic_store(c1, 0, __ATOMIC_RELAXED, __HIP_MEMORY_SCOPE_AGENT);
                asm volatile("s_waitcnt vmcnt(0)" ::: "memory");
                __hip_atomic_store(gen, my + 1, __ATOMIC_RELAXED, __HIP_MEMORY_SCOPE_AGENT);
                rel = true;
            }
        }
        if (!rel) {
            long long t0 = clock64();
            int it = 0;
            while (__hip_atomic_load(gen, __ATOMIC_RELAXED, __HIP_MEMORY_SCOPE_AGENT) == my) {
                __builtin_amdgcn_s_sleep(1);
                if (((++it) & 255) == 0 && clock64() - t0 > 2000000000LL) break;  // escape
            }
        }
    }
    __syncthreads();
}

// ---- software-pipelined coherent K-loop: window of 4 chunk-pairs in flight.
// R2 lesson: 8-deep overflows the 128-VGPR cap (launch_bounds 512x2) -> spills.
// Permuted layout: chunk stride 1024 halves/ks-step, tile m stride 512.
template <int KS, int MT>
struct KStep {
    static __device__ __forceinline__ void run(const _Float16* a0, const _Float16* a1,
                                               half8 (&b0)[4], half8 (&b1)[4],
                                               const half8 (&wf)[2][16],
                                               f32x16 (&acc)[MT][2]) {
        constexpr int slot = KS & 3;
        constexpr int CNT = MT * ((KS + 4 < 16) ? 3 : (15 - KS));
        if constexpr (MT == 2) vwait2<CNT>(b0[slot], b1[slot]);
        else vwait1<CNT>(b0[slot]);
        acc[0][0] = __builtin_amdgcn_mfma_f32_32x32x16_f16(b0[slot], wf[0][KS], acc[0][0], 0, 0, 0);
        acc[0][1] = __builtin_amdgcn_mfma_f32_32x32x16_f16(b0[slot], wf[1][KS], acc[0][1], 0, 0, 0);
        if constexpr (MT == 2) {
            acc[1][0] = __builtin_amdgcn_mfma_f32_32x32x16_f16(b1[slot], wf[0][KS], acc[1][0], 0, 0, 0);
            acc[1][1] = __builtin_amdgcn_mfma_f32_32x32x16_f16(b1[slot], wf[1][KS], acc[1][1], 0, 0, 0);
        }
        if constexpr (KS + 4 < 16) {
            b0[slot] = ldg_llc(a0 + (KS + 4) * 1024);
            if constexpr (MT == 2) b1[slot] = ldg_llc(a1 + (KS + 4) * 1024);
        }
        KStep<KS + 1, MT>::run(a0, a1, b0, b1, wf, acc);
    }
};
template <int MT>
struct KStep<16, MT> {
    static __device__ __forceinline__ void run(const _Float16*, const _Float16*, half8 (&)[4],
                                               half8 (&)[4], const half8 (&)[2][16],
                                               f32x16 (&)[MT][2]) {}
};

template <int MT>
__device__ __forceinline__ void cell_compute_coh(const _Float16* a0, const _Float16* a1,
                                                 const half8 (&wf)[2][16],
                                                 f32x16 (&acc)[MT][2]) {
#pragma unroll
    for (int mt = 0; mt < MT; ++mt)
#pragma unroll
        for (int nt = 0; nt < 2; ++nt)
#pragma unroll
            for (int r = 0; r < 16; ++r) acc[mt][nt][r] = 0.f;
    half8 b0[4], b1[4];
#pragma unroll
    for (int i = 0; i < 4; ++i) {
        b0[i] = ldg_llc(a0 + i * 1024);
        if constexpr (MT == 2) b1[i] = ldg_llc(a1 + i * 1024);
    }
    KStep<0, MT>::run(a0, a1, b0, b1, wf, acc);
}

// plain-cached path (layer-0 embedding reads, row-major ehi): unchanged
template <int MT>
__device__ __forceinline__ void cell_compute_plain(const _Float16* __restrict__ a0,
                                                   const _Float16* __restrict__ a1,
                                                   const half8 (&wf)[2][16],
                                                   f32x16 (&acc)[MT][2]) {
#pragma unroll
    for (int mt = 0; mt < MT; ++mt)
#pragma unroll
        for (int nt = 0; nt < 2; ++nt)
#pragma unroll
            for (int r = 0; r < 16; ++r) acc[mt][nt][r] = 0.f;
#pragma unroll
    for (int ks = 0; ks < 16; ++ks) {
        half8 x0 = *reinterpret_cast<const half8*>(a0 + ks * 16);
        acc[0][0] = __builtin_amdgcn_mfma_f32_32x32x16_f16(x0, wf[0][ks], acc[0][0], 0, 0, 0);
        acc[0][1] = __builtin_amdgcn_mfma_f32_32x32x16_f16(x0, wf[1][ks], acc[0][1], 0, 0, 0);
        if (MT == 2) {
            half8 x1 = *reinterpret_cast<const half8*>(a1 + ks * 16);
            acc[1][0] = __builtin_amdgcn_mfma_f32_32x32x16_f16(x1, wf[0][ks], acc[1][0], 0, 0, 0);
            acc[1][1] = __builtin_amdgcn_mfma_f32_32x32x16_f16(x1, wf[1][ks], acc[1][1], 0, 0, 0);
        }
    }
}

// part write: C layout (32x32): n=lane&31, m=4*(lane>>5)+(r&3)+8*(r>>2)
template <int MT, bool ADD>
__device__ __forceinline__ void part_write(float (*pw)[64], const f32x16 (&acc)[MT][2],
                                           int lane) {
    const int ln = lane & 31;
#pragma unroll
    for (int mt = 0; mt < MT; ++mt)
#pragma unroll
        for (int nt = 0; nt < 2; ++nt)
#pragma unroll
            for (int r = 0; r < 16; ++r) {
                int m = mt * 32 + 4 * (lane >> 5) + (r & 3) + 8 * (r >> 2);
                int n = nt * 32 + ln;
                int idx = n ^ ((m & 7) << 2);
                if (ADD) pw[m][idx] += acc[mt][nt][r];
                else pw[m][idx] = acc[mt][nt][r];
            }
}

// Persistent wavefront LSTM: 256 blocks x 512 threads (8 waves, 2/SIMD).
// Wave w: K-slice 256 (w<4: y/w_ih, w>=4: h/w_hh), full N=64.
__global__ __launch_bounds__(512, 2) void lstm_persistent(
    const int* __restrict__ padded_in, const int* __restrict__ in_lengths,
    const float* __restrict__ w_ih, const float* __restrict__ w_hh,
    const float* __restrict__ biasf, int* __restrict__ bar,
    const _Float16* __restrict__ ehi, _Float16* __restrict__ hbh,
    _Float16* __restrict__ ybh, float* __restrict__ out) {
    __shared__ __align__(16) float part[4][64][64];  // 64 KB

    const int cu = blockIdx.x;
    const int layer = cu >> 6;
    const int j0 = (cu & 63) * 16;
    const int tid = threadIdx.x;
    const int wv = tid >> 6;
    const int lane = tid & 63;
    const int ln = lane & 31;
    const int khalf = (lane >> 5) * 8;
    const bool isH = (wv >= 4);
    const int kb = (isH ? (wv - 4) : wv) * 256;

    // ---- one-time weight preload: fp32 -> fp16 frags, 128 VGPR/lane
    half8 wf[2][16];
    {
        const float* wsrc = isH ? w_hh : w_ih;
#pragma unroll
        for (int nt = 0; nt < 2; ++nt) {
            int n = nt * 32 + ln;
            const float* rowp =
                wsrc + ((size_t)layer * 4 * Hn + (n >> 4) * Hn + j0 + (n & 15)) * Hn + kb + khalf;
#pragma unroll
            for (int ks = 0; ks < 16; ++ks) {
                f32x4 a = *reinterpret_cast<const f32x4*>(rowp + ks * 16);
                f32x4 b = *reinterpret_cast<const f32x4*>(rowp + ks * 16 + 4);
                half8 h;
                h[0] = (_Float16)a[0]; h[1] = (_Float16)a[1];
                h[2] = (_Float16)a[2]; h[3] = (_Float16)a[3];
                h[4] = (_Float16)b[0]; h[5] = (_Float16)b[1];
                h[6] = (_Float16)b[2]; h[7] = (_Float16)b[3];
                wf[nt][ks] = h;
            }
        }
    }

    // epilogue ownership (threads 0..255): batch row brow, 4 units jcol..jcol+3
    const int brow = (tid & 255) >> 2;
    const int jcol = (tid & 3) * 4;
    const int J = j0 + jcol;
    const int po = perm_off(brow, J);  // loop-invariant permuted half-offset
    float bias[4][4];
#pragma unroll
    for (int g = 0; g < 4; ++g)
#pragma unroll
        for (int p = 0; p < 4; ++p)
            bias[g][p] = biasf[layer * 4096 + g * 1024 + J + p];

    float creg[4] = {0.f, 0.f, 0.f, 0.f};
    float hreg[4] = {0.f, 0.f, 0.f, 0.f};

    const bool carryOwner = (tid < 256) && (layer > 0) && (layer < 3);

    for (int w = 0; w < Sn + Ln - 1; ++w) {
        const int t = w - layer;
        if (t >= 0 && t < Sn) {
            const int bs = in_lengths[t];
            const int pin = t & 1;
            const int pout = pin ^ 1;

            // early-issue inactive-row y-carry load (layers 1-2, inactive rows
            // only): pinned above the K-loop asm loads so its LLC latency hides
            // under compute. vmcnt: extra EARLIER loads are conservative-safe.
            half4v ycarry{};
            if (carryOwner && brow >= bs)
                ycarry = ldg_llc4(&ybh[(size_t)(pin * 3 + layer - 1) * BH + po]);

            // per-wave A-source pointers for its K-slice (permuted layout:
            // base + kb*64 + lane*8 halves; ks stride 1024; tile m stride 512)
            const _Float16 *a0, *a1;
            bool coh;
            if (!isH) {
                if (layer == 0) {  // embedding: read-only, cacheable, row-major
                    const int ko = kb + khalf;
                    a0 = ehi + (size_t)padded_in[ln * Sn + t] * Hn + ko;
                    a1 = ehi + (size_t)padded_in[(32 + ln) * Sn + t] * Hn + ko;
                    coh = false;
                } else {
                    const _Float16* base =
                        ybh + (size_t)(pin * 3 + layer - 1) * BH + (size_t)kb * 64 + lane * 8;
                    a0 = base;
                    a1 = base + 512;
                    coh = true;
                }
            } else {
                const _Float16* base =
                    hbh + (size_t)(pin * Ln + layer) * BH + (size_t)kb * 64 + lane * 8;
                a0 = base;
                a1 = base + 512;
                coh = true;
            }

            // compute; two-phase partial accumulation (waves 0-3 store, 4-7 add)
            if (bs > 32) {
                f32x16 acc[2][2];
                if (coh) cell_compute_coh<2>(a0, a1, wf, acc);
                else cell_compute_plain<2>(a0, a1, wf, acc);
                if (wv < 4) part_write<2, false>(part[wv], acc, lane);
                __syncthreads();
                if (wv >= 4) part_write<2, true>(part[wv - 4], acc, lane);
            } else {
                f32x16 acc[1][2];
                if (coh) cell_compute_coh<1>(a0, a1, wf, acc);
                else cell_compute_plain<1>(a0, a1, wf, acc);
                if (wv < 4) part_write<1, false>(part[wv], acc, lane);
                __syncthreads();
                if (wv >= 4) part_write<1, true>(part[wv - 4], acc, lane);
            }
            __syncthreads();

            if (tid < 256) {
                // cross-wave K-reduction + bias
                float gsum[4][4];
#pragma unroll
                for (int g = 0; g < 4; ++g) {
                    int nidx = (g * 16 + jcol) ^ ((brow & 7) << 2);
                    f32x4 s = *reinterpret_cast<const f32x4*>(&part[0][brow][nidx]);
#pragma unroll
                    for (int p2 = 1; p2 < 4; ++p2)
                        s = s + *reinterpret_cast<const f32x4*>(&part[p2][brow][nidx]);
#pragma unroll
                    for (int p = 0; p < 4; ++p) gsum[g][p] = s[p] + bias[g][p];
                }

                const bool active = (brow < bs);
                float hold[4], ysum[4];
#pragma unroll
                for (int p = 0; p < 4; ++p) {
                    float cn = sigmf(gsum[1][p]) * creg[p] + sigmf(gsum[0][p]) * tanhf_(gsum[2][p]);
                    float hn = sigmf(gsum[3][p]) * tanhf_(cn);
                    hold[p] = hreg[p];
                    if (active) { creg[p] = cn; hreg[p] = hn; }
                    ysum[p] = hreg[p] + hold[p];
                }
                {   // h broadcast (fp16, t-parity double buffer, permuted) -> LLC
                    half4v hh;
#pragma unroll
                    for (int p = 0; p < 4; ++p) hh[p] = (_Float16)hreg[p];
                    stg_coh4(&hbh[(size_t)(pout * Ln + layer) * BH + po], hh);
                }
                if (layer < 3) {  // y interface feed (same-parity slot, permuted) -> LLC
                    half4v yh;
                    if (active) {
#pragma unroll
                        for (int p = 0; p < 4; ++p) yh[p] = (_Float16)ysum[p];
                    } else {  // carry incoming y (x_t for l=0) verbatim
                        if (layer == 0) {
                            int ib = padded_in[brow * Sn + t];
                            yh = *reinterpret_cast<const half4v*>(&ehi[(size_t)ib * Hn + J]);
                        } else {
                            yh = ycarry;  // pre-issued at step start
                        }
                    }
                    stg_coh4(&ybh[(size_t)(pin * 3 + layer) * BH + po], yh);
                }
            }
        }
        grid_barrier(bar, cu);
    }

    if (layer == 3 && tid < 256) {
        f32x4 o;
#pragma unroll
        for (int p = 0; p < 4; ++p) o[p] = hreg[p];
        *reinterpret_cast<f32x4*>(&out[(size_t)brow * Hn + J]) = o;
    }
}

extern "C" void kernel_launch(void* const* d_in, const int* in_sizes, int n_in,
                              void* d_out, int out_size, void* d_ws, size_t ws_size,
                              hipStream_t stream) {
    const int* padded_in = (const int*)d_in[0];
    const int* in_lengths = (const int*)d_in[1];
    const float* emb = (const float*)d_in[2];
    const float* w_ih = (const float*)d_in[3];
    const float* w_hh = (const float*)d_in[4];
    const float* b_ih = (const float*)d_in[5];
    const float* b_hh = (const float*)d_in[6];
    float* outp = (float*)d_out;

    // workspace (~2 MB), all segments 16B-aligned
    char* w = (char*)d_ws;
    int* bar = (int*)w;            w += BAR_INTS * 4;
    float* biasf = (float*)w;      w += (size_t)Ln * 4 * Hn * 4;
    _Float16* ehi = (_Float16*)w;  w += (size_t)Vn * Hn * 2;
    _Float16* hbh = (_Float16*)w;  w += (size_t)2 * Ln * Bn * Hn * 2;
    _Float16* ybh = (_Float16*)w;  w += (size_t)2 * 3 * Bn * Hn * 2;

    init_kernel<<<256, 256, 0, stream>>>(b_ih, b_hh, emb, bar, biasf, ehi, hbh);
    lstm_persistent<<<NBLK, 512, 0, stream>>>(padded_in, in_lengths, w_ih, w_hh, biasf, bar,
                                              ehi, hbh, ybh, outp);
}